// Round 8
// baseline (1073.250 us; speedup 1.0000x reference)
//
#include <hip/hip_runtime.h>
#include <hip/hip_bf16.h>
#include <math.h>

#define N_INPUTS 65536
#define NUM_EMB 4096
#define DIM 256
#define TAU_H 9.0e-4f     // half-score threshold (empirically validated r4-r7)
#define CAP 192

typedef __attribute__((ext_vector_type(8))) short bf16x8;
typedef __attribute__((ext_vector_type(4))) float f32x4;

// ---- monotone float<->uint packing ----
__device__ __forceinline__ unsigned enc32(float f) {
    unsigned u = __float_as_uint(f);
    return (u & 0x80000000u) ? ~u : (u | 0x80000000u);
}
__device__ __forceinline__ unsigned short f2bf_rne(float f) {
    unsigned u = __float_as_uint(f);
    return (unsigned short)((u + 0x7FFFu + ((u >> 16) & 1u)) >> 16);
}

// ---- numpy pairwise sum of squares (bit-exact, proven r2) ----
__device__ __forceinline__ float pw128_sq(const float* __restrict__ a) {
    float r[8];
    #pragma unroll
    for (int j = 0; j < 8; ++j) r[j] = __fmul_rn(a[j], a[j]);
    #pragma unroll
    for (int i = 8; i < 128; i += 8)
        #pragma unroll
        for (int j = 0; j < 8; ++j)
            r[j] = __fadd_rn(r[j], __fmul_rn(a[i + j], a[i + j]));
    return __fadd_rn(__fadd_rn(__fadd_rn(r[0], r[1]), __fadd_rn(r[2], r[3])),
                     __fadd_rn(__fadd_rn(r[4], r[5]), __fadd_rn(r[6], r[7])));
}
__device__ __forceinline__ float pw256_sq(const float* __restrict__ a) {
    return __fadd_rn(pw128_sq(a), pw128_sq(a + 128));
}

// ---- prep (codebook): norms + bf16 copy ----
__global__ __launch_bounds__(256) void prep_rows(
        const float* __restrict__ src, float* __restrict__ norms,
        unsigned short* __restrict__ dst_bf) {
    __shared__ float xs[64 * 260];
    const int t = threadIdx.x, b = blockIdx.x;
    const size_t rowbase = (size_t)b * 64;
    const float4* g = (const float4*)(src + rowbase * DIM);
    float4* s4 = (float4*)xs;
    #pragma unroll
    for (int k = 0; k < 16; ++k) {
        int p = t + k * 256, r = p >> 6, c = p & 63;
        s4[r * 65 + c] = g[p];
    }
    __syncthreads();
    if (t < 64) norms[rowbase + t] = pw256_sq(xs + t * 260);
    #pragma unroll
    for (int k = 0; k < 16; ++k) {
        int p = t + k * 256, r = p >> 6, c = p & 63;
        float4 v = s4[r * 65 + c];
        ushort4 u;
        u.x = f2bf_rne(v.x); u.y = f2bf_rne(v.y);
        u.z = f2bf_rne(v.z); u.w = f2bf_rne(v.w);
        ((ushort4*)dst_bf)[(size_t)b * 4096 + p] = u;
    }
}

// ---- exact score, bit-identical to r2 (passed indices exactly) ----
__device__ float exact_score(const float* __restrict__ xr, const float* __restrict__ er,
                             float nx2r, float ne2v) {
    float a = 0.f;
    for (int d = 0; d < DIM; d += 16) {
        float4 xa = *(const float4*)(xr + d);
        float4 xb = *(const float4*)(xr + d + 4);
        float4 xc = *(const float4*)(xr + d + 8);
        float4 xd = *(const float4*)(xr + d + 12);
        float4 e0 = *(const float4*)(er + d);
        float4 e1 = *(const float4*)(er + d + 4);
        float4 e2 = *(const float4*)(er + d + 8);
        float4 e3 = *(const float4*)(er + d + 12);
        a = fmaf(xa.x, e0.x, a); a = fmaf(xa.y, e0.y, a);
        a = fmaf(xa.z, e0.z, a); a = fmaf(xa.w, e0.w, a);
        a = fmaf(xb.x, e1.x, a); a = fmaf(xb.y, e1.y, a);
        a = fmaf(xb.z, e1.z, a); a = fmaf(xb.w, e1.w, a);
        a = fmaf(xc.x, e2.x, a); a = fmaf(xc.y, e2.y, a);
        a = fmaf(xc.z, e2.z, a); a = fmaf(xc.w, e2.w, a);
        a = fmaf(xd.x, e3.x, a); a = fmaf(xd.y, e3.y, a);
        a = fmaf(xd.z, e3.z, a); a = fmaf(xd.w, e3.w, a);
    }
    float t1 = __fadd_rn(nx2r, ne2v);
    return __fsub_rn(t1, __fmul_rn(2.f, a));
}

// ---- pass 1: barrier-free MFMA GEMM, B streamed from L2 to registers ----
// Block = 64 rows, 4 waves (wave grid 1x4). A frags in regs; B direct global
// loads (codebook bf16 = 2 MB, L2-resident). Wave-local prefix-min + append.
#define LOADB(dst, ctv, ttv)                                                   \
    {                                                                          \
        const char* base_ = cbB + (ctv) * 131072 + (ttv) * 128;                \
        _Pragma("unroll")                                                      \
        for (int n_ = 0; n_ < 4; ++n_) {                                       \
            dst[n_][0] = *(const bf16x8*)(base_ + voff[n_]);                   \
            dst[n_][1] = *(const bf16x8*)(base_ + voff[n_] + 64);              \
        }                                                                      \
    }

#define MMSTEP(bg, ttv)                                                        \
    {                                                                          \
        _Pragma("unroll")                                                      \
        for (int kk_ = 0; kk_ < 2; ++kk_)                                      \
            _Pragma("unroll")                                                  \
            for (int m_ = 0; m_ < 4; ++m_)                                     \
                _Pragma("unroll")                                              \
                for (int n_ = 0; n_ < 4; ++n_)                                 \
                    acc[m_][n_] = __builtin_amdgcn_mfma_f32_16x16x32_bf16(     \
                        af[m_][(ttv) * 2 + kk_], bg[n_][kk_], acc[m_][n_], 0, 0, 0); \
    }

__global__ __launch_bounds__(256) void gemm_cand(
        const float* __restrict__ x,
        const unsigned short* __restrict__ cbbf,
        const float* __restrict__ ne2,
        unsigned* __restrict__ cand_cnt,
        unsigned short* __restrict__ cand_ent,
        float* __restrict__ nx2) {
    __shared__ float xs[32 * 260];          // 33280 B
    __shared__ unsigned cnt_s[64];

    const int tid = threadIdx.x;
    const int w = tid >> 6, lane = tid & 63;
    const int wc = w;                        // wave grid 1x4
    const size_t brow = (size_t)blockIdx.x * 64;

    if (tid < 64) cnt_s[tid] = 0u;

    // ---- prologue: stage x in 2 halves of 32 rows; norms + A frags ----
    bf16x8 af[4][8];                         // rows m*16+(lane&15), 8 K-slices
    #pragma unroll
    for (int h = 0; h < 2; ++h) {
        const float4* g = (const float4*)(x + (brow + (size_t)h * 32) * DIM);
        #pragma unroll
        for (int r = 0; r < 8; ++r) {
            int p = tid + r * 256, rr = p >> 6, c = p & 63;
            ((float4*)xs)[rr * 65 + c] = g[p];
        }
        __syncthreads();
        if (tid < 32) nx2[brow + h * 32 + tid] = pw256_sq(xs + tid * 260);
        #pragma unroll
        for (int m2 = 0; m2 < 2; ++m2) {
            #pragma unroll
            for (int ks = 0; ks < 8; ++ks) {
                const float* p = xs + (m2 * 16 + (lane & 15)) * 260 + ks * 32 + (lane >> 4) * 8;
                float4 a = *(const float4*)p, b = *(const float4*)(p + 4);
                bf16x8 v;
                v[0] = (short)f2bf_rne(a.x); v[1] = (short)f2bf_rne(a.y);
                v[2] = (short)f2bf_rne(a.z); v[3] = (short)f2bf_rne(a.w);
                v[4] = (short)f2bf_rne(b.x); v[5] = (short)f2bf_rne(b.y);
                v[6] = (short)f2bf_rne(b.z); v[7] = (short)f2bf_rne(b.w);
                af[h * 2 + m2][ks] = v;
            }
        }
        __syncthreads();
    }

    const char* cbB = (const char*)cbbf;
    int voff[4];
    #pragma unroll
    for (int n = 0; n < 4; ++n)
        voff[n] = ((wc * 64 + n * 16 + (lane & 15)) << 9) + ((lane >> 4) << 4);

    f32x4 acc[4][4];
    #pragma unroll
    for (int m = 0; m < 4; ++m)
        #pragma unroll
        for (int n = 0; n < 4; ++n) acc[m][n] = (f32x4){0.f, 0.f, 0.f, 0.f};

    float pm[4][4];                          // wave-local per-row prefix min
    #pragma unroll
    for (int m = 0; m < 4; ++m)
        #pragma unroll
        for (int j = 0; j < 4; ++j) pm[m][j] = INFINITY;

    bf16x8 bgA[4][2], bgB[4][2];
    LOADB(bgA, 0, 0);

    for (int ct = 0; ct < 16; ++ct) {
        LOADB(bgB, ct, 1);
        MMSTEP(bgA, 0);
        LOADB(bgA, ct, 2);
        MMSTEP(bgB, 1);
        LOADB(bgB, ct, 3);
        MMSTEP(bgA, 2);
        if (ct < 15) { LOADB(bgA, ct + 1, 0); }
        MMSTEP(bgB, 3);

        // ---- wave-local epilogue (no barriers) ----
        float ne2h[4];
        #pragma unroll
        for (int n = 0; n < 4; ++n)
            ne2h[n] = 0.5f * ne2[ct * 256 + wc * 64 + n * 16 + (lane & 15)];

        #pragma unroll
        for (int m = 0; m < 4; ++m) {
            #pragma unroll
            for (int j = 0; j < 4; ++j) {
                float v = fminf(fminf(ne2h[0] - acc[m][0][j], ne2h[1] - acc[m][1][j]),
                                fminf(ne2h[2] - acc[m][2][j], ne2h[3] - acc[m][3][j]));
                #pragma unroll
                for (int off = 1; off < 16; off <<= 1)
                    v = fminf(v, __shfl_xor(v, off, 64));
                float rm = fminf(pm[m][j], v);      // inclusive prefix min
                pm[m][j] = rm;
                float th = rm + TAU_H;
                int row = m * 16 + (lane >> 4) * 4 + j;
                #pragma unroll
                for (int n = 0; n < 4; ++n) {
                    float s = ne2h[n] - acc[m][n][j];
                    if (s <= th) {
                        unsigned pos = atomicAdd(&cnt_s[row], 1u);
                        if (pos < CAP)
                            cand_ent[(brow + row) * CAP + pos] =
                                (unsigned short)(ct * 256 + wc * 64 + n * 16 + (lane & 15));
                    }
                }
                acc[m][0][j] = 0.f; acc[m][1][j] = 0.f;
                acc[m][2][j] = 0.f; acc[m][3][j] = 0.f;
            }
        }
    }

    __syncthreads();
    if (tid < 64) cand_cnt[brow + tid] = cnt_s[tid];
}

// ---- pass 2: exact refine (one wave per row) ----
__global__ __launch_bounds__(256) void refine_kernel(
        const float* __restrict__ x, const float* __restrict__ cb,
        const float* __restrict__ ne2, const float* __restrict__ nx2,
        const unsigned* __restrict__ cand_cnt,
        const unsigned short* __restrict__ cand_ent,
        float* __restrict__ out_idx, int* __restrict__ counts) {
    const size_t row = (size_t)blockIdx.x * 4 + (threadIdx.x >> 6);
    const int lane = threadIdx.x & 63;
    const unsigned cnt = cand_cnt[row];
    const float nx2r = nx2[row];
    const float* xr = x + row * DIM;
    unsigned long long best = ~0ull;

    if (cnt <= CAP) {
        for (unsigned p = lane; p < cnt; p += 64) {
            int code = cand_ent[row * CAP + p];
            float s = exact_score(xr, cb + (size_t)code * DIM, nx2r, ne2[code]);
            unsigned long long pk = ((unsigned long long)enc32(s) << 32) | (unsigned)code;
            best = best < pk ? best : pk;
        }
    }
    #pragma unroll
    for (int off = 1; off < 64; off <<= 1) {
        unsigned long long o = __shfl_xor(best, off, 64);
        best = best < o ? best : o;
    }
    if (best == ~0ull) {   // overflow: exact full scan (always correct)
        unsigned long long b2 = ~0ull;
        for (int c = lane; c < NUM_EMB; c += 64) {
            float s = exact_score(xr, cb + (size_t)c * DIM, nx2r, ne2[c]);
            unsigned long long pk = ((unsigned long long)enc32(s) << 32) | (unsigned)c;
            b2 = b2 < pk ? b2 : pk;
        }
        #pragma unroll
        for (int off = 1; off < 64; off <<= 1) {
            unsigned long long o = __shfl_xor(b2, off, 64);
            b2 = b2 < o ? b2 : o;
        }
        best = b2;
    }
    if (lane == 0) {
        int idx = (int)(best & 0xFFFFFFFFull);
        idx = max(0, min(NUM_EMB - 1, idx));
        out_idx[row] = (float)idx;
        atomicAdd(&counts[idx], 1);
    }
}

// ---- pass 3: gather quantized + loss partials ----
__global__ __launch_bounds__(256) void outputs_kernel(
        const float* __restrict__ x, const float* __restrict__ cb,
        const float* __restrict__ out_idx, float* __restrict__ out_q,
        float* __restrict__ partials) {
    __shared__ float red[256];
    const int t = threadIdx.x, b = blockIdx.x;
    const size_t rowbase = (size_t)b * 64;
    const int r = t >> 2, c0 = (t & 3) * 16;
    const size_t row = rowbase + r;
    int qi = (int)out_idx[row];
    qi = max(0, min(NUM_EMB - 1, qi));
    const float4* crq = (const float4*)(cb + (size_t)qi * DIM);
    const float4* xr4 = (const float4*)(x + row * DIM);
    float4* oq = (float4*)(out_q + row * DIM);
    float ss = 0.f;
    #pragma unroll
    for (int k = 0; k < 16; ++k) {
        float4 q = crq[c0 + k];
        float4 xv = xr4[c0 + k];
        oq[c0 + k] = q;
        float dx = xv.x - q.x, dy = xv.y - q.y, dz = xv.z - q.z, dw = xv.w - q.w;
        ss += dx * dx + dy * dy + dz * dz + dw * dw;
    }
    red[t] = ss; __syncthreads();
    for (int st = 128; st; st >>= 1) {
        if (t < st) red[t] += red[t + st];
        __syncthreads();
    }
    if (t == 0) partials[b] = red[0];
}

__global__ void finalize_kernel(const float* __restrict__ partials, int np,
                                const int* __restrict__ counts,
                                float* __restrict__ out_loss,
                                float* __restrict__ out_perp) {
    __shared__ double sh[256];
    const int t = threadIdx.x;
    double s = 0.0;
    for (int i = t; i < np; i += 256) s += (double)partials[i];
    sh[t] = s; __syncthreads();
    for (int st = 128; st; st >>= 1) { if (t < st) sh[t] += sh[t + st]; __syncthreads(); }
    double sse = sh[0];
    __syncthreads();
    double h = 0.0;
    for (int k = t; k < NUM_EMB; k += 256) {
        double p = (double)counts[k] / (double)N_INPUTS;
        h -= p * log(p + 1e-10);
    }
    sh[t] = h; __syncthreads();
    for (int st = 128; st; st >>= 1) { if (t < st) sh[t] += sh[t + st]; __syncthreads(); }
    if (t == 0) {
        double mse = sse / ((double)N_INPUTS * (double)DIM);
        out_loss[0] = (float)(1.25 * mse);
        out_perp[0] = (float)exp(sh[0]);
    }
}

extern "C" void kernel_launch(void* const* d_in, const int* in_sizes, int n_in,
                              void* d_out, int out_size, void* d_ws, size_t ws_size,
                              hipStream_t stream) {
    const float* x  = (const float*)d_in[0];
    const float* cb = (const float*)d_in[1];
    float* out      = (float*)d_out;

    float* out_q    = out;                           // 16777216 f32 (64 MiB)
    float* out_loss = out + (size_t)N_INPUTS * DIM;
    float* out_perp = out_loss + 1;
    float* out_idx  = out_perp + 1;

    // scratch inside out_q region (rewritten by outputs_kernel at the end)
    char* sc = (char*)out_q;
    unsigned short* cbbf     = (unsigned short*)(sc);                // 2 MB
    unsigned* cand_cnt       = (unsigned*)(sc + 2097152);            // 256 KB
    unsigned short* cand_ent = (unsigned short*)(sc + 4194304);      // 24 MB, ends 28 MB

    float* ne2      = (float*)d_ws;                       // 16 KB
    int*   counts   = (int*)((char*)d_ws + 16384);        // 16 KB
    float* partials = (float*)((char*)d_ws + 32768);      // 4 KB
    float* nx2      = (float*)((char*)d_ws + 36864);      // 256 KB

    hipMemsetAsync(counts, 0, NUM_EMB * sizeof(int), stream);

    prep_rows<<<NUM_EMB / 64, 256, 0, stream>>>(cb, ne2, cbbf);

    gemm_cand<<<N_INPUTS / 64, 256, 0, stream>>>(x, cbbf, ne2, cand_cnt,
                                                 cand_ent, nx2);
    refine_kernel<<<N_INPUTS / 4, 256, 0, stream>>>(x, cb, ne2, nx2, cand_cnt, cand_ent,
                                                    out_idx, counts);
    outputs_kernel<<<N_INPUTS / 64, 256, 0, stream>>>(x, cb, out_idx, out_q, partials);
    finalize_kernel<<<1, 256, 0, stream>>>(partials, N_INPUTS / 64, counts,
                                           out_loss, out_perp);
}

// Round 9
// 863.075 us; speedup vs baseline: 1.2435x; 1.2435x over previous
//
#include <hip/hip_runtime.h>
#include <hip/hip_bf16.h>
#include <math.h>

#define N_INPUTS 65536
#define NUM_EMB 4096
#define DIM 256
#define TAU_H 9.0e-4f     // half-score threshold (empirically validated r4-r8)
#define CAP 64
#define QSC 1.0e6f

typedef __attribute__((ext_vector_type(8))) short bf16x8;
typedef __attribute__((ext_vector_type(4))) float f32x4;

// ---- monotone float<->uint packing ----
__device__ __forceinline__ unsigned enc32(float f) {
    unsigned u = __float_as_uint(f);
    return (u & 0x80000000u) ? ~u : (u | 0x80000000u);
}
__device__ __forceinline__ float dec32(unsigned e) {
    unsigned u = (e & 0x80000000u) ? (e & 0x7FFFFFFFu) : ~e;
    return __uint_as_float(u);
}
__device__ __forceinline__ unsigned short f2bf_rne(float f) {
    unsigned u = __float_as_uint(f);
    return (unsigned short)((u + 0x7FFFu + ((u >> 16) & 1u)) >> 16);
}

// ---- numpy pairwise sum of squares (bit-exact, proven r2) ----
__device__ __forceinline__ float pw128_sq(const float* __restrict__ a) {
    float r[8];
    #pragma unroll
    for (int j = 0; j < 8; ++j) r[j] = __fmul_rn(a[j], a[j]);
    #pragma unroll
    for (int i = 8; i < 128; i += 8)
        #pragma unroll
        for (int j = 0; j < 8; ++j)
            r[j] = __fadd_rn(r[j], __fmul_rn(a[i + j], a[i + j]));
    return __fadd_rn(__fadd_rn(__fadd_rn(r[0], r[1]), __fadd_rn(r[2], r[3])),
                     __fadd_rn(__fadd_rn(r[4], r[5]), __fadd_rn(r[6], r[7])));
}
__device__ __forceinline__ float pw256_sq(const float* __restrict__ a) {
    return __fadd_rn(pw128_sq(a), pw128_sq(a + 128));
}

// ---- prep: stage 64 rows -> row norms (numpy order) + bf16 copy ----
__global__ __launch_bounds__(256) void prep_rows(
        const float* __restrict__ src, float* __restrict__ norms,
        unsigned short* __restrict__ dst_bf) {
    __shared__ float xs[64 * 260];
    const int t = threadIdx.x, b = blockIdx.x;
    const size_t rowbase = (size_t)b * 64;
    const float4* g = (const float4*)(src + rowbase * DIM);
    float4* s4 = (float4*)xs;
    #pragma unroll
    for (int k = 0; k < 16; ++k) {
        int p = t + k * 256, r = p >> 6, c = p & 63;
        s4[r * 65 + c] = g[p];
    }
    __syncthreads();
    if (t < 64) norms[rowbase + t] = pw256_sq(xs + t * 260);
    #pragma unroll
    for (int k = 0; k < 16; ++k) {
        int p = t + k * 256, r = p >> 6, c = p & 63;
        float4 v = s4[r * 65 + c];
        ushort4 u;
        u.x = f2bf_rne(v.x); u.y = f2bf_rne(v.y);
        u.z = f2bf_rne(v.z); u.w = f2bf_rne(v.w);
        ((ushort4*)dst_bf)[(size_t)b * 4096 + p] = u;
    }
}

// ---- exact score, bit-identical to r2 (passed indices exactly) ----
__device__ float exact_score(const float* __restrict__ xr, const float* __restrict__ er,
                             float nx2r, float ne2v) {
    float a = 0.f;
    for (int d = 0; d < DIM; d += 16) {
        float4 xa = *(const float4*)(xr + d);
        float4 xb = *(const float4*)(xr + d + 4);
        float4 xc = *(const float4*)(xr + d + 8);
        float4 xd = *(const float4*)(xr + d + 12);
        float4 e0 = *(const float4*)(er + d);
        float4 e1 = *(const float4*)(er + d + 4);
        float4 e2 = *(const float4*)(er + d + 8);
        float4 e3 = *(const float4*)(er + d + 12);
        a = fmaf(xa.x, e0.x, a); a = fmaf(xa.y, e0.y, a);
        a = fmaf(xa.z, e0.z, a); a = fmaf(xa.w, e0.w, a);
        a = fmaf(xb.x, e1.x, a); a = fmaf(xb.y, e1.y, a);
        a = fmaf(xb.z, e1.z, a); a = fmaf(xb.w, e1.w, a);
        a = fmaf(xc.x, e2.x, a); a = fmaf(xc.y, e2.y, a);
        a = fmaf(xc.z, e2.z, a); a = fmaf(xc.w, e2.w, a);
        a = fmaf(xd.x, e3.x, a); a = fmaf(xd.y, e3.y, a);
        a = fmaf(xd.z, e3.z, a); a = fmaf(xd.w, e3.w, a);
    }
    float t1 = __fadd_rn(nx2r, ne2v);
    return __fsub_rn(t1, __fmul_rn(2.f, a));
}

// ---- pass 1: persistent 128-row block, 2-phase staged MFMA GEMM.
// Epilogue: barrier-free LDS-atomic running min; candidates buffered in LDS,
// flushed once at block end (no scattered global stores in the hot loop).
__global__ __launch_bounds__(512) void gemm_cand(
        const unsigned short* __restrict__ xbf,
        const unsigned short* __restrict__ cbbf,
        const float* __restrict__ ne2,
        unsigned* __restrict__ cand_cnt,
        unsigned* __restrict__ cand_ent,
        unsigned* __restrict__ ma_enc) {
    __shared__ __align__(16) char Bs[65536];          // 2 x 32KB B dbuf (x-stage union)
    __shared__ unsigned cand_lds[128][CAP];           // 32KB
    __shared__ unsigned rmin_u[128];
    __shared__ unsigned cnt_s[128];

    const int tid = threadIdx.x;
    const int w = tid >> 6, lane = tid & 63;
    const int wr = w >> 2, wc = w & 3;                // 2x4 wave grid
    const size_t brow = (size_t)blockIdx.x * 128;
    const int srcoff = ((lane & 7) ^ (lane >> 3)) << 4;

    if (tid < 128) { rmin_u[tid] = 0xFFFFFFFFu; cnt_s[tid] = 0u; }
    for (int i = tid; i < 128 * CAP; i += 512) ((unsigned*)cand_lds)[i] = 0u;

    // ---- prologue: stage x-tile (128 rows x 512B bf16) into Bs, build A frags ----
    #pragma unroll
    for (int q = 0; q < 4; ++q) {
        #pragma unroll
        for (int i = 0; i < 2; ++i) {
            int chunk = w * 2 + i;                    // 0..15, wave-uniform
            int row = chunk * 8 + (lane >> 3);
            const char* ga = (const char*)xbf + (brow + row) * 512 + q * 128 + srcoff;
            __builtin_amdgcn_global_load_lds(
                (const __attribute__((address_space(1))) unsigned*)ga,
                (__attribute__((address_space(3))) unsigned*)(Bs + q * 16384 + chunk * 1024),
                16, 0, 0);
        }
    }
    __syncthreads();
    bf16x8 af[4][8];
    #pragma unroll
    for (int m = 0; m < 4; ++m) {
        int rowl = wr * 64 + m * 16 + (lane & 15);
        #pragma unroll
        for (int ks = 0; ks < 8; ++ks) {
            int q = ks >> 1, kk = ks & 1;
            int gr = (kk * 4 + (lane >> 4)) ^ (rowl & 7);
            af[m][ks] = *(const bf16x8*)(Bs + q * 16384 + rowl * 128 + (gr << 4));
        }
    }
    __syncthreads();

    auto stageB = [&](int buf, int ct, int tt) {
        #pragma unroll
        for (int r = 0; r < 4; ++r) {
            int chunk = r * 8 + w;                    // 0..31, wave-uniform
            int code = ct * 256 + chunk * 8 + (lane >> 3);
            const char* gb = (const char*)cbbf + (size_t)code * 512 + tt * 128 + srcoff;
            __builtin_amdgcn_global_load_lds(
                (const __attribute__((address_space(1))) unsigned*)gb,
                (__attribute__((address_space(3))) unsigned*)(Bs + buf * 32768 + chunk * 1024),
                16, 0, 0);
        }
    };

    f32x4 acc[4][4];
    #pragma unroll
    for (int m = 0; m < 4; ++m)
        #pragma unroll
        for (int n = 0; n < 4; ++n) acc[m][n] = (f32x4){0.f, 0.f, 0.f, 0.f};

    stageB(0, 0, 0);
    __syncthreads();

    for (int ct = 0; ct < 16; ++ct) {
        #pragma unroll
        for (int tt = 0; tt < 4; ++tt) {
            if (!(ct == 15 && tt == 3))
                stageB((tt + 1) & 1, (tt == 3) ? ct + 1 : ct, (tt + 1) & 3);
            const int buf = tt & 1;
            #pragma unroll
            for (int kk = 0; kk < 2; ++kk) {
                bf16x8 bg[4];
                #pragma unroll
                for (int n = 0; n < 4; ++n) {
                    int coll = wc * 64 + n * 16 + (lane & 15);
                    int gr = (kk * 4 + (lane >> 4)) ^ (coll & 7);
                    bg[n] = *(const bf16x8*)(Bs + buf * 32768 + coll * 128 + (gr << 4));
                }
                #pragma unroll
                for (int m = 0; m < 4; ++m)
                    #pragma unroll
                    for (int n = 0; n < 4; ++n)
                        acc[m][n] = __builtin_amdgcn_mfma_f32_16x16x32_bf16(
                            af[m][tt * 2 + kk], bg[n], acc[m][n], 0, 0, 0);
            }
            __syncthreads();
        }

        // ---- barrier-free epilogue for col tile ct ----
        float ne2h[4];
        #pragma unroll
        for (int n = 0; n < 4; ++n)
            ne2h[n] = 0.5f * ne2[ct * 256 + wc * 64 + n * 16 + (lane & 15)];

        #pragma unroll
        for (int m = 0; m < 4; ++m) {
            #pragma unroll
            for (int j = 0; j < 4; ++j) {
                float v = fminf(fminf(ne2h[0] - acc[m][0][j], ne2h[1] - acc[m][1][j]),
                                fminf(ne2h[2] - acc[m][2][j], ne2h[3] - acc[m][3][j]));
                #pragma unroll
                for (int off = 1; off < 16; off <<= 1)
                    v = fminf(v, __shfl_xor(v, off, 64));
                const int rowl = wr * 64 + m * 16 + (lane >> 4) * 4 + j;
                if ((lane & 15) == 0) atomicMin(&rmin_u[rowl], enc32(v));
                // threshold: own wave's v folded in directly; other waves' updates
                // may be stale -> only looser (superset), correctness preserved.
                float th = fminf(dec32(rmin_u[rowl]), v) + TAU_H;
                #pragma unroll
                for (int n = 0; n < 4; ++n) {
                    float s = ne2h[n] - acc[m][n][j];
                    if (s <= th) {
                        int col = ct * 256 + wc * 64 + n * 16 + (lane & 15);
                        int q = (int)rintf(s * QSC) + 32768;
                        q = max(0, min(65535, q));
                        unsigned pos = atomicAdd(&cnt_s[rowl], 1u);
                        if (pos < CAP)
                            cand_lds[rowl][pos] = ((unsigned)q << 16) | (unsigned)col;
                    }
                }
                acc[m][0][j] = 0.f; acc[m][1][j] = 0.f;
                acc[m][2][j] = 0.f; acc[m][3][j] = 0.f;
            }
        }
    }

    // ---- single coalesced flush ----
    __syncthreads();
    for (int i = tid; i < 128 * CAP; i += 512) {
        int row = i >> 6, c = i & (CAP - 1);
        cand_ent[(brow + row) * CAP + c] = cand_lds[row][c];
    }
    if (tid < 128) {
        cand_cnt[brow + tid] = cnt_s[tid];
        ma_enc[brow + tid] = rmin_u[tid];
    }
}

// ---- pass 2: exact refine (one wave per row, q-prefiltered) ----
__global__ __launch_bounds__(256) void refine_kernel(
        const float* __restrict__ x, const float* __restrict__ cb,
        const float* __restrict__ ne2, const float* __restrict__ nx2,
        const unsigned* __restrict__ cand_cnt,
        const unsigned* __restrict__ cand_ent,
        const unsigned* __restrict__ ma_enc,
        float* __restrict__ out_idx, int* __restrict__ counts) {
    const size_t row = (size_t)blockIdx.x * 4 + (threadIdx.x >> 6);
    const int lane = threadIdx.x & 63;
    const unsigned cnt = cand_cnt[row];
    const float nx2r = nx2[row];
    const float* xr = x + row * DIM;
    unsigned long long best = ~0ull;

    if (cnt <= CAP) {
        float mav = dec32(ma_enc[row]);
        int qthr = (int)rintf((mav + TAU_H) * QSC) + 1 + 32768;
        for (unsigned p = lane; p < cnt; p += 64) {
            unsigned e = cand_ent[row * CAP + p];
            if ((int)(e >> 16) <= qthr) {
                int code = (int)(e & 0xFFFFu);
                float s = exact_score(xr, cb + (size_t)code * DIM, nx2r, ne2[code]);
                unsigned long long pk = ((unsigned long long)enc32(s) << 32) | (unsigned)code;
                best = best < pk ? best : pk;
            }
        }
    }
    #pragma unroll
    for (int off = 1; off < 64; off <<= 1) {
        unsigned long long o = __shfl_xor(best, off, 64);
        best = best < o ? best : o;
    }
    if (best == ~0ull) {   // overflow / empty: exact full scan (always correct)
        unsigned long long b2 = ~0ull;
        for (int c = lane; c < NUM_EMB; c += 64) {
            float s = exact_score(xr, cb + (size_t)c * DIM, nx2r, ne2[c]);
            unsigned long long pk = ((unsigned long long)enc32(s) << 32) | (unsigned)c;
            b2 = b2 < pk ? b2 : pk;
        }
        #pragma unroll
        for (int off = 1; off < 64; off <<= 1) {
            unsigned long long o = __shfl_xor(b2, off, 64);
            b2 = b2 < o ? b2 : o;
        }
        best = b2;
    }
    if (lane == 0) {
        int idx = (int)(best & 0xFFFFFFFFull);
        idx = max(0, min(NUM_EMB - 1, idx));
        out_idx[row] = (float)idx;
        atomicAdd(&counts[idx], 1);
    }
}

// ---- pass 3: gather quantized + loss partials ----
__global__ __launch_bounds__(256) void outputs_kernel(
        const float* __restrict__ x, const float* __restrict__ cb,
        const float* __restrict__ out_idx, float* __restrict__ out_q,
        float* __restrict__ partials) {
    __shared__ float red[256];
    const int t = threadIdx.x, b = blockIdx.x;
    const size_t rowbase = (size_t)b * 64;
    const int r = t >> 2, c0 = (t & 3) * 16;
    const size_t row = rowbase + r;
    int qi = (int)out_idx[row];
    qi = max(0, min(NUM_EMB - 1, qi));
    const float4* crq = (const float4*)(cb + (size_t)qi * DIM);
    const float4* xr4 = (const float4*)(x + row * DIM);
    float4* oq = (float4*)(out_q + row * DIM);
    float ss = 0.f;
    #pragma unroll
    for (int k = 0; k < 16; ++k) {
        float4 q = crq[c0 + k];
        float4 xv = xr4[c0 + k];
        oq[c0 + k] = q;
        float dx = xv.x - q.x, dy = xv.y - q.y, dz = xv.z - q.z, dw = xv.w - q.w;
        ss += dx * dx + dy * dy + dz * dz + dw * dw;
    }
    red[t] = ss; __syncthreads();
    for (int st = 128; st; st >>= 1) {
        if (t < st) red[t] += red[t + st];
        __syncthreads();
    }
    if (t == 0) partials[b] = red[0];
}

__global__ void finalize_kernel(const float* __restrict__ partials, int np,
                                const int* __restrict__ counts,
                                float* __restrict__ out_loss,
                                float* __restrict__ out_perp) {
    __shared__ double sh[256];
    const int t = threadIdx.x;
    double s = 0.0;
    for (int i = t; i < np; i += 256) s += (double)partials[i];
    sh[t] = s; __syncthreads();
    for (int st = 128; st; st >>= 1) { if (t < st) sh[t] += sh[t + st]; __syncthreads(); }
    double sse = sh[0];
    __syncthreads();
    double h = 0.0;
    for (int k = t; k < NUM_EMB; k += 256) {
        double p = (double)counts[k] / (double)N_INPUTS;
        h -= p * log(p + 1e-10);
    }
    sh[t] = h; __syncthreads();
    for (int st = 128; st; st >>= 1) { if (t < st) sh[t] += sh[t + st]; __syncthreads(); }
    if (t == 0) {
        double mse = sse / ((double)N_INPUTS * (double)DIM);
        out_loss[0] = (float)(1.25 * mse);
        out_perp[0] = (float)exp(sh[0]);
    }
}

extern "C" void kernel_launch(void* const* d_in, const int* in_sizes, int n_in,
                              void* d_out, int out_size, void* d_ws, size_t ws_size,
                              hipStream_t stream) {
    const float* x  = (const float*)d_in[0];
    const float* cb = (const float*)d_in[1];
    float* out      = (float*)d_out;

    float* out_q    = out;                           // 16777216 f32 (64 MiB)
    float* out_loss = out + (size_t)N_INPUTS * DIM;
    float* out_perp = out_loss + 1;
    float* out_idx  = out_perp + 1;

    // scratch inside out_q region (rewritten by outputs_kernel at the end)
    char* sc = (char*)out_q;
    unsigned short* cbbf = (unsigned short*)(sc);                    // 2 MB @0
    unsigned short* xbf  = (unsigned short*)(sc + 2097152);          // 32 MB @2MB
    unsigned* cand_cnt   = (unsigned*)(sc + 35651584);               // 256 KB @34MB
    unsigned* ma_enc     = (unsigned*)(sc + 35913728);               // 256 KB
    unsigned* cand_ent   = (unsigned*)(sc + 36700160);               // 16 MB @35MB, ends 51MB

    float* ne2      = (float*)d_ws;                       // 16 KB
    int*   counts   = (int*)((char*)d_ws + 16384);        // 16 KB
    float* partials = (float*)((char*)d_ws + 32768);      // 4 KB
    float* nx2      = (float*)((char*)d_ws + 36864);      // 256 KB

    hipMemsetAsync(counts, 0, NUM_EMB * sizeof(int), stream);

    prep_rows<<<NUM_EMB / 64, 256, 0, stream>>>(cb, ne2, cbbf);
    prep_rows<<<N_INPUTS / 64, 256, 0, stream>>>(x, nx2, xbf);

    gemm_cand<<<N_INPUTS / 128, 512, 0, stream>>>(xbf, cbbf, ne2, cand_cnt,
                                                  cand_ent, ma_enc);
    refine_kernel<<<N_INPUTS / 4, 256, 0, stream>>>(x, cb, ne2, nx2, cand_cnt, cand_ent,
                                                    ma_enc, out_idx, counts);
    outputs_kernel<<<N_INPUTS / 64, 256, 0, stream>>>(x, cb, out_idx, out_q, partials);
    finalize_kernel<<<1, 256, 0, stream>>>(partials, N_INPUTS / 64, counts,
                                           out_loss, out_perp);
}

// Round 10
// 694.561 us; speedup vs baseline: 1.5452x; 1.2426x over previous
//
#include <hip/hip_runtime.h>
#include <hip/hip_bf16.h>
#include <math.h>

#define N_INPUTS 65536
#define NUM_EMB 4096
#define DIM 256
#define TAU_H 9.0e-4f     // half-score threshold (empirically validated r4-r9)
#define CAP 128
#define QSC 1.0e6f

typedef __attribute__((ext_vector_type(8))) short bf16x8;
typedef __attribute__((ext_vector_type(4))) float f32x4;

// ---- monotone float<->uint packing ----
__device__ __forceinline__ unsigned enc32(float f) {
    unsigned u = __float_as_uint(f);
    return (u & 0x80000000u) ? ~u : (u | 0x80000000u);
}
__device__ __forceinline__ float dec32(unsigned e) {
    unsigned u = (e & 0x80000000u) ? (e & 0x7FFFFFFFu) : ~e;
    return __uint_as_float(u);
}
__device__ __forceinline__ unsigned short f2bf_rne(float f) {
    unsigned u = __float_as_uint(f);
    return (unsigned short)((u + 0x7FFFu + ((u >> 16) & 1u)) >> 16);
}

// ---- numpy pairwise sum of squares (bit-exact, proven r2) ----
__device__ __forceinline__ float pw128_sq(const float* __restrict__ a) {
    float r[8];
    #pragma unroll
    for (int j = 0; j < 8; ++j) r[j] = __fmul_rn(a[j], a[j]);
    #pragma unroll
    for (int i = 8; i < 128; i += 8)
        #pragma unroll
        for (int j = 0; j < 8; ++j)
            r[j] = __fadd_rn(r[j], __fmul_rn(a[i + j], a[i + j]));
    return __fadd_rn(__fadd_rn(__fadd_rn(r[0], r[1]), __fadd_rn(r[2], r[3])),
                     __fadd_rn(__fadd_rn(r[4], r[5]), __fadd_rn(r[6], r[7])));
}
__device__ __forceinline__ float pw256_sq(const float* __restrict__ a) {
    return __fadd_rn(pw128_sq(a), pw128_sq(a + 128));
}

// ---- prep: stage 64 rows -> row norms (numpy order) + bf16 copy ----
__global__ __launch_bounds__(256) void prep_rows(
        const float* __restrict__ src, float* __restrict__ norms,
        unsigned short* __restrict__ dst_bf) {
    __shared__ float xs[64 * 260];
    const int t = threadIdx.x, b = blockIdx.x;
    const size_t rowbase = (size_t)b * 64;
    const float4* g = (const float4*)(src + rowbase * DIM);
    float4* s4 = (float4*)xs;
    #pragma unroll
    for (int k = 0; k < 16; ++k) {
        int p = t + k * 256, r = p >> 6, c = p & 63;
        s4[r * 65 + c] = g[p];
    }
    __syncthreads();
    if (t < 64) norms[rowbase + t] = pw256_sq(xs + t * 260);
    #pragma unroll
    for (int k = 0; k < 16; ++k) {
        int p = t + k * 256, r = p >> 6, c = p & 63;
        float4 v = s4[r * 65 + c];
        ushort4 u;
        u.x = f2bf_rne(v.x); u.y = f2bf_rne(v.y);
        u.z = f2bf_rne(v.z); u.w = f2bf_rne(v.w);
        ((ushort4*)dst_bf)[(size_t)b * 4096 + p] = u;
    }
}

// ---- exact score, bit-identical to r2 (passed indices exactly) ----
__device__ float exact_score(const float* __restrict__ xr, const float* __restrict__ er,
                             float nx2r, float ne2v) {
    float a = 0.f;
    for (int d = 0; d < DIM; d += 16) {
        float4 xa = *(const float4*)(xr + d);
        float4 xb = *(const float4*)(xr + d + 4);
        float4 xc = *(const float4*)(xr + d + 8);
        float4 xd = *(const float4*)(xr + d + 12);
        float4 e0 = *(const float4*)(er + d);
        float4 e1 = *(const float4*)(er + d + 4);
        float4 e2 = *(const float4*)(er + d + 8);
        float4 e3 = *(const float4*)(er + d + 12);
        a = fmaf(xa.x, e0.x, a); a = fmaf(xa.y, e0.y, a);
        a = fmaf(xa.z, e0.z, a); a = fmaf(xa.w, e0.w, a);
        a = fmaf(xb.x, e1.x, a); a = fmaf(xb.y, e1.y, a);
        a = fmaf(xb.z, e1.z, a); a = fmaf(xb.w, e1.w, a);
        a = fmaf(xc.x, e2.x, a); a = fmaf(xc.y, e2.y, a);
        a = fmaf(xc.z, e2.z, a); a = fmaf(xc.w, e2.w, a);
        a = fmaf(xd.x, e3.x, a); a = fmaf(xd.y, e3.y, a);
        a = fmaf(xd.z, e3.z, a); a = fmaf(xd.w, e3.w, a);
    }
    float t1 = __fadd_rn(nx2r, ne2v);
    return __fsub_rn(t1, __fmul_rn(2.f, a));
}

// ---- pass 1: persistent 128-row block, 2-phase staged MFMA GEMM.
// Barrier-free LDS-atomic running min; candidates buffered in LDS (CAP=128),
// flushed once at block end ONTO the block's own consumed x-panel (stride match).
__global__ __launch_bounds__(512) void gemm_cand(
        const unsigned short* __restrict__ xbf,
        const unsigned short* __restrict__ cbbf,
        const float* __restrict__ ne2,
        unsigned* __restrict__ cand_cnt,
        unsigned* __restrict__ cand_ent,     // aliases xbf (see launch)
        unsigned* __restrict__ ma_enc) {
    __shared__ __align__(16) char Bs[65536];          // 2 x 32KB B dbuf (x-stage union)
    __shared__ unsigned cand_lds[128][CAP];           // 64KB
    __shared__ unsigned rmin_u[128];
    __shared__ unsigned cnt_s[128];

    const int tid = threadIdx.x;
    const int w = tid >> 6, lane = tid & 63;
    const int wr = w >> 2, wc = w & 3;                // 2x4 wave grid
    const size_t brow = (size_t)blockIdx.x * 128;
    const int srcoff = ((lane & 7) ^ (lane >> 3)) << 4;

    if (tid < 128) { rmin_u[tid] = 0xFFFFFFFFu; cnt_s[tid] = 0u; }

    // ---- prologue: stage x-tile (128 rows x 512B bf16) into Bs, build A frags ----
    #pragma unroll
    for (int q = 0; q < 4; ++q) {
        #pragma unroll
        for (int i = 0; i < 2; ++i) {
            int chunk = w * 2 + i;                    // 0..15, wave-uniform
            int row = chunk * 8 + (lane >> 3);
            const char* ga = (const char*)xbf + (brow + row) * 512 + q * 128 + srcoff;
            __builtin_amdgcn_global_load_lds(
                (const __attribute__((address_space(1))) unsigned*)ga,
                (__attribute__((address_space(3))) unsigned*)(Bs + q * 16384 + chunk * 1024),
                16, 0, 0);
        }
    }
    __syncthreads();
    bf16x8 af[4][8];
    #pragma unroll
    for (int m = 0; m < 4; ++m) {
        int rowl = wr * 64 + m * 16 + (lane & 15);
        #pragma unroll
        for (int ks = 0; ks < 8; ++ks) {
            int q = ks >> 1, kk = ks & 1;
            int gr = (kk * 4 + (lane >> 4)) ^ (rowl & 7);
            af[m][ks] = *(const bf16x8*)(Bs + q * 16384 + rowl * 128 + (gr << 4));
        }
    }
    __syncthreads();

    auto stageB = [&](int buf, int ct, int tt) {
        #pragma unroll
        for (int r = 0; r < 4; ++r) {
            int chunk = r * 8 + w;                    // 0..31, wave-uniform
            int code = ct * 256 + chunk * 8 + (lane >> 3);
            const char* gb = (const char*)cbbf + (size_t)code * 512 + tt * 128 + srcoff;
            __builtin_amdgcn_global_load_lds(
                (const __attribute__((address_space(1))) unsigned*)gb,
                (__attribute__((address_space(3))) unsigned*)(Bs + buf * 32768 + chunk * 1024),
                16, 0, 0);
        }
    };

    f32x4 acc[4][4];
    #pragma unroll
    for (int m = 0; m < 4; ++m)
        #pragma unroll
        for (int n = 0; n < 4; ++n) acc[m][n] = (f32x4){0.f, 0.f, 0.f, 0.f};

    stageB(0, 0, 0);
    __syncthreads();

    for (int ct = 0; ct < 16; ++ct) {
        #pragma unroll
        for (int tt = 0; tt < 4; ++tt) {
            if (!(ct == 15 && tt == 3))
                stageB((tt + 1) & 1, (tt == 3) ? ct + 1 : ct, (tt + 1) & 3);
            const int buf = tt & 1;
            #pragma unroll
            for (int kk = 0; kk < 2; ++kk) {
                bf16x8 bg[4];
                #pragma unroll
                for (int n = 0; n < 4; ++n) {
                    int coll = wc * 64 + n * 16 + (lane & 15);
                    int gr = (kk * 4 + (lane >> 4)) ^ (coll & 7);
                    bg[n] = *(const bf16x8*)(Bs + buf * 32768 + coll * 128 + (gr << 4));
                }
                #pragma unroll
                for (int m = 0; m < 4; ++m)
                    #pragma unroll
                    for (int n = 0; n < 4; ++n)
                        acc[m][n] = __builtin_amdgcn_mfma_f32_16x16x32_bf16(
                            af[m][tt * 2 + kk], bg[n], acc[m][n], 0, 0, 0);
            }
            __syncthreads();
        }

        // ---- barrier-free epilogue for col tile ct ----
        float ne2h[4];
        #pragma unroll
        for (int n = 0; n < 4; ++n)
            ne2h[n] = 0.5f * ne2[ct * 256 + wc * 64 + n * 16 + (lane & 15)];

        #pragma unroll
        for (int m = 0; m < 4; ++m) {
            #pragma unroll
            for (int j = 0; j < 4; ++j) {
                float v = fminf(fminf(ne2h[0] - acc[m][0][j], ne2h[1] - acc[m][1][j]),
                                fminf(ne2h[2] - acc[m][2][j], ne2h[3] - acc[m][3][j]));
                #pragma unroll
                for (int off = 1; off < 16; off <<= 1)
                    v = fminf(v, __shfl_xor(v, off, 64));
                const int rowl = wr * 64 + m * 16 + (lane >> 4) * 4 + j;
                if ((lane & 15) == 0) atomicMin(&rmin_u[rowl], enc32(v));
                // stale reads of rmin_u only loosen the threshold (superset).
                float th = fminf(dec32(rmin_u[rowl]), v) + TAU_H;
                #pragma unroll
                for (int n = 0; n < 4; ++n) {
                    float s = ne2h[n] - acc[m][n][j];
                    if (s <= th) {
                        int col = ct * 256 + wc * 64 + n * 16 + (lane & 15);
                        int q = (int)rintf(s * QSC) + 32768;
                        q = max(0, min(65535, q));
                        unsigned pos = atomicAdd(&cnt_s[rowl], 1u);
                        if (pos < CAP)
                            cand_lds[rowl][pos] = ((unsigned)q << 16) | (unsigned)col;
                    }
                }
                acc[m][0][j] = 0.f; acc[m][1][j] = 0.f;
                acc[m][2][j] = 0.f; acc[m][3][j] = 0.f;
            }
        }
    }

    // ---- single coalesced flush (uint4) onto own consumed x-panel ----
    __syncthreads();
    {
        uint4* dst = (uint4*)(cand_ent + brow * CAP);
        const uint4* srcl = (const uint4*)&cand_lds[0][0];
        #pragma unroll
        for (int k = 0; k < 8; ++k)
            dst[tid + k * 512] = srcl[tid + k * 512];
    }
    if (tid < 128) {
        cand_cnt[brow + tid] = cnt_s[tid];
        ma_enc[brow + tid] = rmin_u[tid];
    }
}

// ---- pass 2: exact refine (one wave per row, q-prefiltered) ----
__global__ __launch_bounds__(256) void refine_kernel(
        const float* __restrict__ x, const float* __restrict__ cb,
        const float* __restrict__ ne2, const float* __restrict__ nx2,
        const unsigned* __restrict__ cand_cnt,
        const unsigned* __restrict__ cand_ent,
        const unsigned* __restrict__ ma_enc,
        float* __restrict__ out_idx, int* __restrict__ counts) {
    const size_t row = (size_t)blockIdx.x * 4 + (threadIdx.x >> 6);
    const int lane = threadIdx.x & 63;
    const unsigned cnt = cand_cnt[row];
    const float nx2r = nx2[row];
    const float* xr = x + row * DIM;
    unsigned long long best = ~0ull;

    if (cnt <= CAP) {
        float mav = dec32(ma_enc[row]);
        int qthr = (int)rintf((mav + TAU_H) * QSC) + 1 + 32768;
        for (unsigned p = lane; p < cnt; p += 64) {
            unsigned e = cand_ent[row * CAP + p];
            if ((int)(e >> 16) <= qthr) {
                int code = (int)(e & 0xFFFFu);
                float s = exact_score(xr, cb + (size_t)code * DIM, nx2r, ne2[code]);
                unsigned long long pk = ((unsigned long long)enc32(s) << 32) | (unsigned)code;
                best = best < pk ? best : pk;
            }
        }
    }
    #pragma unroll
    for (int off = 1; off < 64; off <<= 1) {
        unsigned long long o = __shfl_xor(best, off, 64);
        best = best < o ? best : o;
    }
    if (best == ~0ull) {   // overflow / empty: exact full scan (always correct)
        unsigned long long b2 = ~0ull;
        for (int c = lane; c < NUM_EMB; c += 64) {
            float s = exact_score(xr, cb + (size_t)c * DIM, nx2r, ne2[c]);
            unsigned long long pk = ((unsigned long long)enc32(s) << 32) | (unsigned)c;
            b2 = b2 < pk ? b2 : pk;
        }
        #pragma unroll
        for (int off = 1; off < 64; off <<= 1) {
            unsigned long long o = __shfl_xor(b2, off, 64);
            b2 = b2 < o ? b2 : o;
        }
        best = b2;
    }
    if (lane == 0) {
        int idx = (int)(best & 0xFFFFFFFFull);
        idx = max(0, min(NUM_EMB - 1, idx));
        out_idx[row] = (float)idx;
        atomicAdd(&counts[idx], 1);
    }
}

// ---- pass 3: gather quantized + loss partials ----
__global__ __launch_bounds__(256) void outputs_kernel(
        const float* __restrict__ x, const float* __restrict__ cb,
        const float* __restrict__ out_idx, float* __restrict__ out_q,
        float* __restrict__ partials) {
    __shared__ float red[256];
    const int t = threadIdx.x, b = blockIdx.x;
    const size_t rowbase = (size_t)b * 64;
    const int r = t >> 2, c0 = (t & 3) * 16;
    const size_t row = rowbase + r;
    int qi = (int)out_idx[row];
    qi = max(0, min(NUM_EMB - 1, qi));
    const float4* crq = (const float4*)(cb + (size_t)qi * DIM);
    const float4* xr4 = (const float4*)(x + row * DIM);
    float4* oq = (float4*)(out_q + row * DIM);
    float ss = 0.f;
    #pragma unroll
    for (int k = 0; k < 16; ++k) {
        float4 q = crq[c0 + k];
        float4 xv = xr4[c0 + k];
        oq[c0 + k] = q;
        float dx = xv.x - q.x, dy = xv.y - q.y, dz = xv.z - q.z, dw = xv.w - q.w;
        ss += dx * dx + dy * dy + dz * dz + dw * dw;
    }
    red[t] = ss; __syncthreads();
    for (int st = 128; st; st >>= 1) {
        if (t < st) red[t] += red[t + st];
        __syncthreads();
    }
    if (t == 0) partials[b] = red[0];
}

__global__ void finalize_kernel(const float* __restrict__ partials, int np,
                                const int* __restrict__ counts,
                                float* __restrict__ out_loss,
                                float* __restrict__ out_perp) {
    __shared__ double sh[256];
    const int t = threadIdx.x;
    double s = 0.0;
    for (int i = t; i < np; i += 256) s += (double)partials[i];
    sh[t] = s; __syncthreads();
    for (int st = 128; st; st >>= 1) { if (t < st) sh[t] += sh[t + st]; __syncthreads(); }
    double sse = sh[0];
    __syncthreads();
    double h = 0.0;
    for (int k = t; k < NUM_EMB; k += 256) {
        double p = (double)counts[k] / (double)N_INPUTS;
        h -= p * log(p + 1e-10);
    }
    sh[t] = h; __syncthreads();
    for (int st = 128; st; st >>= 1) { if (t < st) sh[t] += sh[t + st]; __syncthreads(); }
    if (t == 0) {
        double mse = sse / ((double)N_INPUTS * (double)DIM);
        out_loss[0] = (float)(1.25 * mse);
        out_perp[0] = (float)exp(sh[0]);
    }
}

extern "C" void kernel_launch(void* const* d_in, const int* in_sizes, int n_in,
                              void* d_out, int out_size, void* d_ws, size_t ws_size,
                              hipStream_t stream) {
    const float* x  = (const float*)d_in[0];
    const float* cb = (const float*)d_in[1];
    float* out      = (float*)d_out;

    float* out_q    = out;                           // 16777216 f32 (64 MiB)
    float* out_loss = out + (size_t)N_INPUTS * DIM;
    float* out_perp = out_loss + 1;
    float* out_idx  = out_perp + 1;

    // scratch inside out_q region (rewritten by outputs_kernel at the end).
    // cand_ent ALIASES xbf: per-row stride match (512 B), each gemm block
    // consumes its own x-panel before flushing candidates onto it.
    char* sc = (char*)out_q;
    unsigned short* cbbf = (unsigned short*)(sc);                    // 2 MB @0
    unsigned short* xbf  = (unsigned short*)(sc + 2097152);          // 32 MB @2MB
    unsigned* cand_ent   = (unsigned*)(sc + 2097152);                // alias of xbf
    unsigned* cand_cnt   = (unsigned*)(sc + 35651584);               // 256 KB @34MB
    unsigned* ma_enc     = (unsigned*)(sc + 35913728);               // 256 KB

    float* ne2      = (float*)d_ws;                       // 16 KB
    int*   counts   = (int*)((char*)d_ws + 16384);        // 16 KB
    float* partials = (float*)((char*)d_ws + 32768);      // 4 KB
    float* nx2      = (float*)((char*)d_ws + 36864);      // 256 KB

    hipMemsetAsync(counts, 0, NUM_EMB * sizeof(int), stream);

    prep_rows<<<NUM_EMB / 64, 256, 0, stream>>>(cb, ne2, cbbf);
    prep_rows<<<N_INPUTS / 64, 256, 0, stream>>>(x, nx2, xbf);

    gemm_cand<<<N_INPUTS / 128, 512, 0, stream>>>(xbf, cbbf, ne2, cand_cnt,
                                                  cand_ent, ma_enc);
    refine_kernel<<<N_INPUTS / 4, 256, 0, stream>>>(x, cb, ne2, nx2, cand_cnt, cand_ent,
                                                    ma_enc, out_idx, counts);
    outputs_kernel<<<N_INPUTS / 64, 256, 0, stream>>>(x, cb, out_idx, out_q, partials);
    finalize_kernel<<<1, 256, 0, stream>>>(partials, N_INPUTS / 64, counts,
                                           out_loss, out_perp);
}